// Round 10
// baseline (192.143 us; speedup 1.0000x reference)
//
#include <hip/hip_runtime.h>
#include <hip/hip_bf16.h>
#include <math.h>

#define Bsz 2
#define Tseq 2048
#define Cdim 1024
#define Hn 16
#define HDim 64
#define Mrows 4096
#define N3 3072
#define QSCALE 0.1803368801111137f   /* 0.125 * log2(e) baked into Q */

typedef __bf16 bf16_t;
typedef __bf16 bf16x4 __attribute__((ext_vector_type(4)));
typedef __bf16 bf16x8 __attribute__((ext_vector_type(8)));
typedef float floatx4 __attribute__((ext_vector_type(4)));

__device__ __forceinline__ void async16(const void* g, void* l) {
    __builtin_amdgcn_global_load_lds(
        (const __attribute__((address_space(1))) void*)g,
        (__attribute__((address_space(3))) void*)l, 16, 0, 0);
}

// ---------------------------------------------------------------------------
// prep: fused fp32->bf16 convert of x + transpose-convert of w_attn, w_proj.
// blocks 0..2047: convert; 2048..5119: w_attn^T; 5120..6143: w_proj^T.
// ---------------------------------------------------------------------------
__global__ __launch_bounds__(256) void prep_kernel(
    const float* __restrict__ x, const float* __restrict__ w_attn,
    const float* __restrict__ w_proj, bf16_t* __restrict__ xb,
    bf16_t* __restrict__ waT, bf16_t* __restrict__ wpT)
{
    __shared__ float Ts[32][33];
    const int bid = blockIdx.x;
    if (bid < 2048) {
        size_t g = (size_t)bid * 256 + threadIdx.x;
        float4 a = *(const float4*)(x + g * 8);
        float4 b = *(const float4*)(x + g * 8 + 4);
        bf16x8 o;
        o[0] = (bf16_t)a.x; o[1] = (bf16_t)a.y; o[2] = (bf16_t)a.z; o[3] = (bf16_t)a.w;
        o[4] = (bf16_t)b.x; o[5] = (bf16_t)b.y; o[6] = (bf16_t)b.z; o[7] = (bf16_t)b.w;
        *(bf16x8*)(xb + g * 8) = o;
        return;
    }
    const float* in; bf16_t* out; int R, C, bx, by;
    if (bid < 5120) {
        int t = bid - 2048; in = w_attn; out = waT; R = Cdim; C = N3;
        bx = t % 96; by = t / 96;
    } else {
        int t = bid - 5120; in = w_proj; out = wpT; R = Cdim; C = Cdim;
        bx = t & 31; by = t >> 5;
    }
    int c0 = bx << 5, r0 = by << 5;
    int lr = threadIdx.x >> 3, lc = (threadIdx.x & 7) << 2;
    float4 v = *(const float4*)(in + (size_t)(r0 + lr) * C + c0 + lc);
    Ts[lr][lc] = v.x; Ts[lr][lc + 1] = v.y; Ts[lr][lc + 2] = v.z; Ts[lr][lc + 3] = v.w;
    __syncthreads();
    bf16x4 o;
    o[0] = (bf16_t)Ts[lc + 0][lr]; o[1] = (bf16_t)Ts[lc + 1][lr];
    o[2] = (bf16_t)Ts[lc + 2][lr]; o[3] = (bf16_t)Ts[lc + 3][lr];
    *(bf16x4*)(out + (size_t)(c0 + lr) * R + r0 + lc) = o;
}

// ---------------------------------------------------------------------------
// QKV GEMM, r16 = EXACT r5/r8 body (measured 45.2-45.8us; 7 structural
// variants all regressed — this is the session's structure ceiling for qkv).
// m97-style loop + XCD-chunked remap (FETCH 21.6MB).
// Epilogue: bias + rotary(q,k) + QSCALE; v -> (BH,HD,T) sigma-permuted.
// ---------------------------------------------------------------------------
__global__ __launch_bounds__(256) void gemm_qkv(
    const bf16_t* __restrict__ xb, const bf16_t* __restrict__ waT,
    const float* __restrict__ bias, const float* __restrict__ cosb,
    const float* __restrict__ sinb,
    bf16_t* __restrict__ qb, bf16_t* __restrict__ kb, bf16_t* __restrict__ vt)
{
    __shared__ bf16_t As[128 * 32];
    __shared__ bf16_t Bs[128 * 32];
    const int tid = threadIdx.x;
    const int lane = tid & 63, w = tid >> 6;
    const int lm = lane & 15, quad = lane >> 4;
    const int wy = w >> 1, wx = w & 1;
    const int bid = blockIdx.x;
    const int xcd = bid & 7, i5 = bid >> 3;
    const int gn = ((xcd & 1) * 12) + (i5 % 12);
    const int gm = ((xcd >> 1) * 8) + (i5 / 12);
    const int m0 = gm << 7, n0 = gn << 7;

    const floatx4 fz = {0.f, 0.f, 0.f, 0.f};
    floatx4 acc[4][4];
    #pragma unroll
    for (int i = 0; i < 4; i++)
        #pragma unroll
        for (int j = 0; j < 4; j++) acc[i][j] = fz;

    const bf16_t* Ag = xb + (size_t)m0 * Cdim;
    const bf16_t* Bg = waT + (size_t)n0 * Cdim;

    for (int k0 = 0; k0 < Cdim; k0 += 32) {
        #pragma unroll
        for (int it = 0; it < 2; ++it) {
            int ci = (w << 7) + (it << 6) + lane;
            int row = ci >> 2, cq = (ci & 3) ^ (row & 3);
            async16(Ag + (size_t)row * Cdim + k0 + cq * 8, As + ((w << 7) + (it << 6)) * 8);
            async16(Bg + (size_t)row * Cdim + k0 + cq * 8, Bs + ((w << 7) + (it << 6)) * 8);
        }
        __syncthreads();
        bf16x8 af[4], bfr[4];
        #pragma unroll
        for (int i = 0; i < 4; i++) {
            int row = (wy << 6) + (i << 4) + lm;
            int cq = quad ^ (lm & 3);
            af[i] = *(const bf16x8*)&As[row * 32 + cq * 8];
        }
        #pragma unroll
        for (int j = 0; j < 4; j++) {
            int row = (wx << 6) + (j << 4) + lm;
            int cq = quad ^ (lm & 3);
            bfr[j] = *(const bf16x8*)&Bs[row * 32 + cq * 8];
        }
        #pragma unroll
        for (int i = 0; i < 4; i++)
            #pragma unroll
            for (int j = 0; j < 4; j++)
                acc[i][j] = __builtin_amdgcn_mfma_f32_16x16x32_bf16(af[i], bfr[j], acc[i][j], 0, 0, 0);
        __syncthreads();
    }

    const int sec = n0 >> 10;                 // block-uniform: 0=q 1=k 2=v
    const int mb = m0 + (wy << 6);
    const int nb = n0 + (wx << 6);
    #pragma unroll
    for (int i = 0; i < 4; i++) {
        int mrow0 = mb + (i << 4) + (quad << 2);
        int b = mrow0 >> 11, t0 = mrow0 & 2047;
        #pragma unroll
        for (int j = 0; j < 4; j++) {
            int n = nb + (j << 4) + lm;
            float bi = bias[n];
            int rel = n & 1023;
            int h = rel >> 6, hd = rel & 63;
            if (sec == 2) {
                int tp = (t0 & ~31) | (((t0 >> 2) & 3) << 3) | (((t0 >> 4) & 1) << 2);
                bf16x4 pk;
                #pragma unroll
                for (int r = 0; r < 4; r++) pk[r] = (bf16_t)(acc[i][j][r] + bi);
                *(bf16x4*)&vt[((size_t)(b * Hn + h) * HDim + hd) * Tseq + tp] = pk;
            } else {
                bf16_t* dst = (sec == 0) ? qb : kb;
                const int ih = hd >> 1;
                const bool ev = !(hd & 1);
                #pragma unroll
                for (int r = 0; r < 4; r++) {
                    int t = t0 + r;
                    float v = acc[i][j][r] + bi;
                    float x = __shfl_xor(v, 1);        // rotary pair partner
                    float c = cosb[t * 32 + ih], s = sinb[t * 32 + ih];
                    float rv = ev ? (v * c - x * s) : (x * s + v * c);
                    if (sec == 0) rv *= QSCALE;
                    dst[((size_t)(b * Hn + h) * Tseq + t) * HDim + hd] = (bf16_t)rv;
                }
            }
        }
    }
}

// ---------------------------------------------------------------------------
// Flash attention, r16: QBLK 64->128, 512 threads (8 waves), 512 blocks.
// The r14 counted-vmcnt pipeline (validated, -2.6us) pays its barrier +
// drain tax once per 64 q-rows; per-iter cost ~1380cyc vs ~450 content.
// Doubling the q-tile halves barrier events AND K/V staging traffic per
// q-row; wave count/CU unchanged (2 blk x 8 waves = 16, VGPR-capped same
// as 4x4). Each wave owns 16 q-rows; causal via per-lane lastk = qq>>6
// (waves above diagonal skip compute, keep staging+barriers; only the
// final k-iter has idle waves). bid&7 = bh&7 keeps XCD K/V locality.
// Staging: 2 loads/thread/tile -> steady-state vmcnt(2), 0 on last iter.
// NO-MAX softmax P=exp2(s), l=sum(P); PV = V^T P^T, sigma baked into vt.
// ---------------------------------------------------------------------------
__global__ __launch_bounds__(512) void attn_mfma(
    const bf16_t* __restrict__ qb, const bf16_t* __restrict__ kb,
    const bf16_t* __restrict__ vt, bf16_t* __restrict__ yb)
{
    __shared__ bf16_t Ks[3][64 * 64];       // 24 KB
    __shared__ bf16_t VTs[3][64 * 64];      // 24 KB

    const int bid = blockIdx.x;
    const int jt = 15 - (bid >> 5);          // 128-row q-tile; long first
    const int bh = bid & 31;
    const int b = bh >> 4, h = bh & 15;
    const int tid = threadIdx.x;
    const int w4 = tid >> 6;                 // 0..7
    const int lane = tid & 63, lm = lane & 15, quad = lane >> 4;
    const int nk = (jt << 1) + 2;            // k-tiles 0 .. 2jt+1 (>=2)

    const bf16_t* Kg0 = kb + (size_t)bh * Tseq * HDim;
    const bf16_t* Vg0 = vt + (size_t)bh * HDim * Tseq;

    // loop-invariant Q fragments (B-operand: n=lm, k); drain before staging
    const int qq = (jt << 7) + (w4 << 4) + lm;   // this lane's q row
    const int lastk = qq >> 6;                   // diagonal k-tile index
    bf16x8 qf[2];
    {
        const bf16_t* Qg = qb + ((size_t)bh * Tseq + qq) * HDim;
        #pragma unroll
        for (int ks = 0; ks < 2; ++ks)
            qf[ks] = *(const bf16x8*)(Qg + (ks << 5) + (quad << 3));
    }
    asm volatile("s_waitcnt vmcnt(0)" ::: "memory");

    auto stagef = [&](int tile, int buf) {       // 2 loads/thread (512 thr)
        const bf16_t* Kg = Kg0 + (size_t)(tile << 6) * HDim;
        const bf16_t* Vg = Vg0 + (tile << 6);
        int ci = tid;                            // chunk 0..511
        int row = ci >> 3, cq = (ci & 7) ^ (row & 7);
        async16(Kg + row * HDim + cq * 8, &Ks[buf][(w4 << 6) * 8]);
        async16(Vg + (size_t)row * Tseq + cq * 8, &VTs[buf][(w4 << 6) * 8]);
    };

    stagef(0, 0);
    stagef(1, 1);                            // nk >= 2 always

    const floatx4 fz = {0.f, 0.f, 0.f, 0.f};
    floatx4 o_[4];                           // O^T: [d-subtile]
    #pragma unroll
    for (int f = 0; f < 4; ++f) o_[f] = fz;
    float l_ = 0.f;

    int cb = 0, sb = 2;                      // cb=kt%3, sb=(kt+2)%3
    for (int kt = 0; kt < nk; ++kt) {
        if (kt == nk - 1) { asm volatile("s_waitcnt vmcnt(0)" ::: "memory"); }
        else             { asm volatile("s_waitcnt vmcnt(2)" ::: "memory"); }
        __builtin_amdgcn_s_barrier();
        __builtin_amdgcn_sched_barrier(0);
        if (kt + 2 < nk) stagef(kt + 2, sb);

        if (kt <= lastk) {
            // S^T = K Q^T (rows = keys, cols = q)
            floatx4 st[4];
            #pragma unroll
            for (int sub = 0; sub < 4; ++sub) st[sub] = fz;
            #pragma unroll
            for (int ks = 0; ks < 2; ++ks) {
                bf16x8 kf[4];
                #pragma unroll
                for (int sub = 0; sub < 4; ++sub) {
                    int krow = (sub << 4) + lm;
                    int kc = ((ks << 2) + quad) ^ (krow & 7);
                    kf[sub] = *(const bf16x8*)&Ks[cb][krow * 64 + kc * 8];
                }
                #pragma unroll
                for (int sub = 0; sub < 4; ++sub)
                    st[sub] = __builtin_amdgcn_mfma_f32_16x16x32_bf16(
                        kf[sub], qf[ks], st[sub], 0, 0, 0);
            }

            // no-max softmax: P = exp2(s) (bf16), l += sum(P)
            const bool dm = (kt == lastk);    // diagonal tile -> causal mask
            bf16x8 pf[2];                     // B-operand P frags (key halves)
            float rs = 0.f;
            #pragma unroll
            for (int cc = 0; cc < 2; ++cc)
                #pragma unroll
                for (int jj = 0; jj < 8; ++jj) {
                    int sub = (cc << 1) + (jj >> 2), r = jj & 3;
                    float val = st[sub][r];
                    if (dm) {
                        int key = (kt << 6) + (sub << 4) + (quad << 2) + r;
                        if (key > qq) val = -3e38f;
                    }
                    float p = exp2f(val);
                    rs += p;
                    pf[cc][jj] = (bf16_t)p;
                }
            rs += __shfl_xor(rs, 16);
            rs += __shfl_xor(rs, 32);
            l_ += rs;

            // O^T += V^T P^T (sigma key-permutation baked into vt layout)
            #pragma unroll
            for (int cc = 0; cc < 2; ++cc) {
                bf16x8 vf[4];
                #pragma unroll
                for (int f = 0; f < 4; ++f) {
                    int vrow = (f << 4) + lm;
                    int vc = ((cc << 2) + quad) ^ (vrow & 7);
                    vf[f] = *(const bf16x8*)&VTs[cb][vrow * 64 + vc * 8];
                }
                #pragma unroll
                for (int f = 0; f < 4; ++f)
                    o_[f] = __builtin_amdgcn_mfma_f32_16x16x32_bf16(
                        vf[f], pf[cc], o_[f], 0, 0, 0);
            }
        }
        sb = cb; cb = (cb == 2) ? 0 : cb + 1;
    }

    // epilogue: O^T lane holds q=qq, d = f*16+quad*4+r
    {
        float inv = 1.f / l_;
        size_t base = ((size_t)(b * Tseq) + qq) * Cdim + (h << 6) + (quad << 2);
        #pragma unroll
        for (int f = 0; f < 4; ++f) {
            bf16x4 ov;
            #pragma unroll
            for (int r = 0; r < 4; ++r) ov[r] = (bf16_t)(o_[f][r] * inv);
            *(bf16x4*)&yb[base + (f << 4)] = ov;
        }
    }
}

// ---------------------------------------------------------------------------
// Proj GEMM, r13 form (128x64 tile, 512 blocks, 2/CU — measured parity with
// 128x128; kept).
// ---------------------------------------------------------------------------
__global__ __launch_bounds__(256) void gemm_proj(
    const bf16_t* __restrict__ yb, const bf16_t* __restrict__ wpT,
    const float* __restrict__ bias, float* __restrict__ out)
{
    __shared__ bf16_t As[128 * 32];
    __shared__ bf16_t Bs[64 * 32];
    const int tid = threadIdx.x;
    const int lane = tid & 63, w = tid >> 6;
    const int lm = lane & 15, quad = lane >> 4;
    const int wy = w >> 1, wx = w & 1;
    const int bid = blockIdx.x;
    const int xcd = bid & 7, idx = bid >> 3;     // idx 0..63
    const int gm = (xcd << 2) + (idx >> 4);      // 0..31
    const int gn = idx & 15;                     // 0..15
    const int m0 = gm << 7, n0 = gn << 6;

    const floatx4 fz = {0.f, 0.f, 0.f, 0.f};
    floatx4 acc[4][2];
    #pragma unroll
    for (int i = 0; i < 4; i++)
        #pragma unroll
        for (int j = 0; j < 2; j++) acc[i][j] = fz;

    const bf16_t* Ag = yb + (size_t)m0 * Cdim;
    const bf16_t* Bg = wpT + (size_t)n0 * Cdim;

    for (int k0 = 0; k0 < Cdim; k0 += 32) {
        #pragma unroll
        for (int it = 0; it < 2; ++it) {         // A: 512 chunks
            int ci = (w << 7) + (it << 6) + lane;
            int row = ci >> 2, cq = (ci & 3) ^ (row & 3);
            async16(Ag + (size_t)row * Cdim + k0 + cq * 8, As + ((w << 7) + (it << 6)) * 8);
        }
        {                                        // B: 256 chunks (1/thread)
            int ci = tid;
            int row = ci >> 2, cq = (ci & 3) ^ (row & 3);
            async16(Bg + (size_t)row * Cdim + k0 + cq * 8, Bs + (w << 6) * 8);
        }
        __syncthreads();
        bf16x8 af[4], bfr[2];
        #pragma unroll
        for (int i = 0; i < 4; i++) {
            int row = (wy << 6) + (i << 4) + lm;
            int cq = quad ^ (lm & 3);
            af[i] = *(const bf16x8*)&As[row * 32 + cq * 8];
        }
        #pragma unroll
        for (int j = 0; j < 2; j++) {
            int row = (wx << 5) + (j << 4) + lm;
            int cq = quad ^ (lm & 3);
            bfr[j] = *(const bf16x8*)&Bs[row * 32 + cq * 8];
        }
        #pragma unroll
        for (int i = 0; i < 4; i++)
            #pragma unroll
            for (int j = 0; j < 2; j++)
                acc[i][j] = __builtin_amdgcn_mfma_f32_16x16x32_bf16(af[i], bfr[j], acc[i][j], 0, 0, 0);
        __syncthreads();
    }

    const int mb = m0 + (wy << 6);
    const int nb = n0 + (wx << 5);
    #pragma unroll
    for (int i = 0; i < 4; i++) {
        int mrow0 = mb + (i << 4) + (quad << 2);
        #pragma unroll
        for (int j = 0; j < 2; j++) {
            int n = nb + (j << 4) + lm;
            float bi = bias[n];
            #pragma unroll
            for (int r = 0; r < 4; r++)
                out[(size_t)(mrow0 + r) * Cdim + n] = acc[i][j][r] + bi;
        }
    }
}

extern "C" void kernel_launch(void* const* d_in, const int* in_sizes, int n_in,
                              void* d_out, int out_size, void* d_ws, size_t ws_size,
                              hipStream_t stream) {
    const float* x      = (const float*)d_in[0];
    const float* cosb   = (const float*)d_in[1];
    const float* sinb   = (const float*)d_in[2];
    const float* w_attn = (const float*)d_in[3];
    const float* b_attn = (const float*)d_in[4];
    const float* w_proj = (const float*)d_in[5];
    const float* b_proj = (const float*)d_in[6];

    char* ws = (char*)d_ws;
    bf16_t* xb  = (bf16_t*)(ws);                       //  8 MB: x bf16 (M,K)
    bf16_t* waT = (bf16_t*)(ws + (size_t)(8 << 20));   //  6 MB: w_attn^T (N,K)
    bf16_t* wpT = (bf16_t*)(ws + (size_t)(14 << 20));  //  2 MB: w_proj^T (N,K)
    bf16_t* qb  = (bf16_t*)(ws + (size_t)(16 << 20));  //  8 MB: q bf16 (BH,T,HD), pre-scaled
    bf16_t* kb  = (bf16_t*)(ws + (size_t)(24 << 20));  //  8 MB: k bf16 (BH,T,HD)
    bf16_t* vtb = (bf16_t*)(ws + (size_t)(32 << 20));  //  8 MB: v^T bf16 (BH,HD,T), key-permuted
    bf16_t* yb  = (bf16_t*)(ws + (size_t)(40 << 20));  //  8 MB: attn out (M,C)

    prep_kernel<<<6144, 256, 0, stream>>>(x, w_attn, w_proj, xb, waT, wpT);
    gemm_qkv<<<768, 256, 0, stream>>>(xb, waT, b_attn, cosb, sinb, qb, kb, vtb);
    attn_mfma<<<512, 512, 0, stream>>>(qb, kb, vtb, yb);
    gemm_proj<<<512, 256, 0, stream>>>(yb, wpT, b_proj, (float*)d_out);
}

// Round 11
// 182.735 us; speedup vs baseline: 1.0515x; 1.0515x over previous
//
#include <hip/hip_runtime.h>
#include <hip/hip_bf16.h>
#include <math.h>

#define Bsz 2
#define Tseq 2048
#define Cdim 1024
#define Hn 16
#define HDim 64
#define Mrows 4096
#define N3 3072
#define QSCALE 0.1803368801111137f   /* 0.125 * log2(e) baked into Q */

typedef __bf16 bf16_t;
typedef __bf16 bf16x4 __attribute__((ext_vector_type(4)));
typedef __bf16 bf16x8 __attribute__((ext_vector_type(8)));
typedef float floatx4 __attribute__((ext_vector_type(4)));

__device__ __forceinline__ void async16(const void* g, void* l) {
    __builtin_amdgcn_global_load_lds(
        (const __attribute__((address_space(1))) void*)g,
        (__attribute__((address_space(3))) void*)l, 16, 0, 0);
}

// ---------------------------------------------------------------------------
// prep: fused fp32->bf16 convert of x + transpose-convert of w_attn, w_proj.
// blocks 0..2047: convert; 2048..5119: w_attn^T; 5120..6143: w_proj^T.
// ---------------------------------------------------------------------------
__global__ __launch_bounds__(256) void prep_kernel(
    const float* __restrict__ x, const float* __restrict__ w_attn,
    const float* __restrict__ w_proj, bf16_t* __restrict__ xb,
    bf16_t* __restrict__ waT, bf16_t* __restrict__ wpT)
{
    __shared__ float Ts[32][33];
    const int bid = blockIdx.x;
    if (bid < 2048) {
        size_t g = (size_t)bid * 256 + threadIdx.x;
        float4 a = *(const float4*)(x + g * 8);
        float4 b = *(const float4*)(x + g * 8 + 4);
        bf16x8 o;
        o[0] = (bf16_t)a.x; o[1] = (bf16_t)a.y; o[2] = (bf16_t)a.z; o[3] = (bf16_t)a.w;
        o[4] = (bf16_t)b.x; o[5] = (bf16_t)b.y; o[6] = (bf16_t)b.z; o[7] = (bf16_t)b.w;
        *(bf16x8*)(xb + g * 8) = o;
        return;
    }
    const float* in; bf16_t* out; int R, C, bx, by;
    if (bid < 5120) {
        int t = bid - 2048; in = w_attn; out = waT; R = Cdim; C = N3;
        bx = t % 96; by = t / 96;
    } else {
        int t = bid - 5120; in = w_proj; out = wpT; R = Cdim; C = Cdim;
        bx = t & 31; by = t >> 5;
    }
    int c0 = bx << 5, r0 = by << 5;
    int lr = threadIdx.x >> 3, lc = (threadIdx.x & 7) << 2;
    float4 v = *(const float4*)(in + (size_t)(r0 + lr) * C + c0 + lc);
    Ts[lr][lc] = v.x; Ts[lr][lc + 1] = v.y; Ts[lr][lc + 2] = v.z; Ts[lr][lc + 3] = v.w;
    __syncthreads();
    bf16x4 o;
    o[0] = (bf16_t)Ts[lc + 0][lr]; o[1] = (bf16_t)Ts[lc + 1][lr];
    o[2] = (bf16_t)Ts[lc + 2][lr]; o[3] = (bf16_t)Ts[lc + 3][lr];
    *(bf16x4*)(out + (size_t)(c0 + lr) * R + r0 + lc) = o;
}

// ---------------------------------------------------------------------------
// QKV GEMM = r5 body (measured 44-46us across 5 reruns; 7 structural
// variants — dbuf x2, BK=64, 8-phase 256^2, static triple-buffer — all
// regressed). m97-style loop + XCD-chunked remap (FETCH 38->21.6MB).
// Epilogue: bias + rotary(q,k) + QSCALE; v -> (BH,HD,T) sigma-permuted so
// attn's PV B-operand comes straight from P registers.
// ---------------------------------------------------------------------------
__global__ __launch_bounds__(256) void gemm_qkv(
    const bf16_t* __restrict__ xb, const bf16_t* __restrict__ waT,
    const float* __restrict__ bias, const float* __restrict__ cosb,
    const float* __restrict__ sinb,
    bf16_t* __restrict__ qb, bf16_t* __restrict__ kb, bf16_t* __restrict__ vt)
{
    __shared__ bf16_t As[128 * 32];
    __shared__ bf16_t Bs[128 * 32];
    const int tid = threadIdx.x;
    const int lane = tid & 63, w = tid >> 6;
    const int lm = lane & 15, quad = lane >> 4;
    const int wy = w >> 1, wx = w & 1;
    const int bid = blockIdx.x;
    const int xcd = bid & 7, i5 = bid >> 3;
    const int gn = ((xcd & 1) * 12) + (i5 % 12);
    const int gm = ((xcd >> 1) * 8) + (i5 / 12);
    const int m0 = gm << 7, n0 = gn << 7;

    const floatx4 fz = {0.f, 0.f, 0.f, 0.f};
    floatx4 acc[4][4];
    #pragma unroll
    for (int i = 0; i < 4; i++)
        #pragma unroll
        for (int j = 0; j < 4; j++) acc[i][j] = fz;

    const bf16_t* Ag = xb + (size_t)m0 * Cdim;
    const bf16_t* Bg = waT + (size_t)n0 * Cdim;

    for (int k0 = 0; k0 < Cdim; k0 += 32) {
        #pragma unroll
        for (int it = 0; it < 2; ++it) {
            int ci = (w << 7) + (it << 6) + lane;
            int row = ci >> 2, cq = (ci & 3) ^ (row & 3);
            async16(Ag + (size_t)row * Cdim + k0 + cq * 8, As + ((w << 7) + (it << 6)) * 8);
            async16(Bg + (size_t)row * Cdim + k0 + cq * 8, Bs + ((w << 7) + (it << 6)) * 8);
        }
        __syncthreads();
        bf16x8 af[4], bfr[4];
        #pragma unroll
        for (int i = 0; i < 4; i++) {
            int row = (wy << 6) + (i << 4) + lm;
            int cq = quad ^ (lm & 3);
            af[i] = *(const bf16x8*)&As[row * 32 + cq * 8];
        }
        #pragma unroll
        for (int j = 0; j < 4; j++) {
            int row = (wx << 6) + (j << 4) + lm;
            int cq = quad ^ (lm & 3);
            bfr[j] = *(const bf16x8*)&Bs[row * 32 + cq * 8];
        }
        #pragma unroll
        for (int i = 0; i < 4; i++)
            #pragma unroll
            for (int j = 0; j < 4; j++)
                acc[i][j] = __builtin_amdgcn_mfma_f32_16x16x32_bf16(af[i], bfr[j], acc[i][j], 0, 0, 0);
        __syncthreads();
    }

    const int sec = n0 >> 10;                 // block-uniform: 0=q 1=k 2=v
    const int mb = m0 + (wy << 6);
    const int nb = n0 + (wx << 6);
    #pragma unroll
    for (int i = 0; i < 4; i++) {
        int mrow0 = mb + (i << 4) + (quad << 2);
        int b = mrow0 >> 11, t0 = mrow0 & 2047;
        #pragma unroll
        for (int j = 0; j < 4; j++) {
            int n = nb + (j << 4) + lm;
            float bi = bias[n];
            int rel = n & 1023;
            int h = rel >> 6, hd = rel & 63;
            if (sec == 2) {
                int tp = (t0 & ~31) | (((t0 >> 2) & 3) << 3) | (((t0 >> 4) & 1) << 2);
                bf16x4 pk;
                #pragma unroll
                for (int r = 0; r < 4; r++) pk[r] = (bf16_t)(acc[i][j][r] + bi);
                *(bf16x4*)&vt[((size_t)(b * Hn + h) * HDim + hd) * Tseq + tp] = pk;
            } else {
                bf16_t* dst = (sec == 0) ? qb : kb;
                const int ih = hd >> 1;
                const bool ev = !(hd & 1);
                #pragma unroll
                for (int r = 0; r < 4; r++) {
                    int t = t0 + r;
                    float v = acc[i][j][r] + bi;
                    float x = __shfl_xor(v, 1);        // rotary pair partner
                    float c = cosb[t * 32 + ih], s = sinb[t * 32 + ih];
                    float rv = ev ? (v * c - x * s) : (x * s + v * c);
                    if (sec == 0) rv *= QSCALE;
                    dst[((size_t)(b * Hn + h) * Tseq + t) * HDim + hd] = (bf16_t)rv;
                }
            }
        }
    }
}

// ---------------------------------------------------------------------------
// Flash attention = r14 (best measured: total 182.5us). Counted-vmcnt
// triple-buffer pipeline: 64-row q-tile, 1024 blocks x 256 threads,
// 3 blocks/CU (48KB LDS), prefetch distance 2, ONE raw s_barrier/iter,
// vmcnt(4) steady state (0 only on the last iter). QBLK=128 variant
// regressed (occupancy collapse to ~8 waves/CU); kept at 64.
// NO-MAX softmax P=exp2(s) (scores bounded), l=sum(P), normalize in
// epilogue. PV = V^T P^T with key permutation sigma baked into vt.
// ---------------------------------------------------------------------------
__global__ __launch_bounds__(256) void attn_mfma(
    const bf16_t* __restrict__ qb, const bf16_t* __restrict__ kb,
    const bf16_t* __restrict__ vt, bf16_t* __restrict__ yb)
{
    __shared__ bf16_t Ks[3][64 * 64];       // 24 KB
    __shared__ bf16_t VTs[3][64 * 64];      // 24 KB

    const int bid = blockIdx.x;
    const int jt = 31 - (bid >> 5);          // long blocks dispatch first
    const int bh = bid & 31;
    const int b = bh >> 4, h = bh & 15;
    const int tid = threadIdx.x;
    const int w4 = tid >> 6, lane = tid & 63, lm = lane & 15, quad = lane >> 4;
    const int nk = jt + 1;                   // kt = 0 .. jt (causal)

    const bf16_t* Kg0 = kb + (size_t)bh * Tseq * HDim;
    const bf16_t* Vg0 = vt + (size_t)bh * HDim * Tseq;

    // loop-invariant Q fragments (B-operand: n=lm, k); drain before staging
    const int qq = (jt << 6) + (w4 << 4) + lm;   // this lane's q row
    bf16x8 qf[2];
    {
        const bf16_t* Qg = qb + ((size_t)bh * Tseq + qq) * HDim;
        #pragma unroll
        for (int ks = 0; ks < 2; ++ks)
            qf[ks] = *(const bf16x8*)(Qg + (ks << 5) + (quad << 3));
    }
    asm volatile("s_waitcnt vmcnt(0)" ::: "memory");

    auto stagef = [&](int tile, int buf) {
        const bf16_t* Kg = Kg0 + (size_t)(tile << 6) * HDim;
        const bf16_t* Vg = Vg0 + (tile << 6);
        #pragma unroll
        for (int it = 0; it < 2; ++it) {
            int ci = (it << 8) + tid;
            int row = ci >> 3, cq = (ci & 7) ^ (row & 7);
            async16(Kg + row * HDim + cq * 8, &Ks[buf][((it << 8) + (w4 << 6)) * 8]);
            async16(Vg + (size_t)row * Tseq + cq * 8, &VTs[buf][((it << 8) + (w4 << 6)) * 8]);
        }
    };

    stagef(0, 0);                            // 4 loads/thread
    if (nk > 1) stagef(1, 1);                // 4 more

    const floatx4 fz = {0.f, 0.f, 0.f, 0.f};
    floatx4 o_[4];                           // O^T: [d-subtile]
    #pragma unroll
    for (int f = 0; f < 4; ++f) o_[f] = fz;
    float l_ = 0.f;

    int cb = 0, sb = 2;                      // cb=kt%3, sb=(kt+2)%3
    for (int kt = 0; kt < nk; ++kt) {
        if (kt == nk - 1) { asm volatile("s_waitcnt vmcnt(0)" ::: "memory"); }
        else             { asm volatile("s_waitcnt vmcnt(4)" ::: "memory"); }
        __builtin_amdgcn_s_barrier();
        __builtin_amdgcn_sched_barrier(0);
        if (kt + 2 < nk) stagef(kt + 2, sb);

        // S^T = K Q^T (rows = keys, cols = q)
        floatx4 st[4];
        #pragma unroll
        for (int sub = 0; sub < 4; ++sub) st[sub] = fz;
        #pragma unroll
        for (int ks = 0; ks < 2; ++ks) {
            bf16x8 kf[4];
            #pragma unroll
            for (int sub = 0; sub < 4; ++sub) {
                int krow = (sub << 4) + lm;
                int kc = ((ks << 2) + quad) ^ (krow & 7);
                kf[sub] = *(const bf16x8*)&Ks[cb][krow * 64 + kc * 8];
            }
            #pragma unroll
            for (int sub = 0; sub < 4; ++sub)
                st[sub] = __builtin_amdgcn_mfma_f32_16x16x32_bf16(
                    kf[sub], qf[ks], st[sub], 0, 0, 0);
        }

        // no-max softmax: P = exp2(s) (bf16), l += sum(P)
        const bool dm = (kt == jt);           // diagonal tile -> causal mask
        bf16x8 pf[2];                         // B-operand P frags (key halves)
        float rs = 0.f;
        #pragma unroll
        for (int cc = 0; cc < 2; ++cc)
            #pragma unroll
            for (int jj = 0; jj < 8; ++jj) {
                int sub = (cc << 1) + (jj >> 2), r = jj & 3;
                float val = st[sub][r];
                if (dm) {
                    int key = (kt << 6) + (sub << 4) + (quad << 2) + r;
                    if (key > qq) val = -3e38f;
                }
                float p = exp2f(val);
                rs += p;
                pf[cc][jj] = (bf16_t)p;
            }
        rs += __shfl_xor(rs, 16);
        rs += __shfl_xor(rs, 32);
        l_ += rs;

        // O^T += V^T P^T (sigma key-permutation baked into vt layout)
        #pragma unroll
        for (int cc = 0; cc < 2; ++cc) {
            bf16x8 vf[4];
            #pragma unroll
            for (int f = 0; f < 4; ++f) {
                int vrow = (f << 4) + lm;
                int vc = ((cc << 2) + quad) ^ (vrow & 7);
                vf[f] = *(const bf16x8*)&VTs[cb][vrow * 64 + vc * 8];
            }
            #pragma unroll
            for (int f = 0; f < 4; ++f)
                o_[f] = __builtin_amdgcn_mfma_f32_16x16x32_bf16(
                    vf[f], pf[cc], o_[f], 0, 0, 0);
        }
        sb = cb; cb = (cb == 2) ? 0 : cb + 1;
    }

    // epilogue: O^T lane holds q=qq, d = f*16+quad*4+r
    {
        float inv = 1.f / l_;
        size_t base = ((size_t)(b * Tseq) + qq) * Cdim + (h << 6) + (quad << 2);
        #pragma unroll
        for (int f = 0; f < 4; ++f) {
            bf16x4 ov;
            #pragma unroll
            for (int r = 0; r < 4; ++r) ov[r] = (bf16_t)(o_[f][r] * inv);
            *(bf16x4*)&yb[base + (f << 4)] = ov;
        }
    }
}

// ---------------------------------------------------------------------------
// Proj GEMM, 128x64 tile, 512 blocks, 2/CU (measured parity with 128x128).
// ---------------------------------------------------------------------------
__global__ __launch_bounds__(256) void gemm_proj(
    const bf16_t* __restrict__ yb, const bf16_t* __restrict__ wpT,
    const float* __restrict__ bias, float* __restrict__ out)
{
    __shared__ bf16_t As[128 * 32];
    __shared__ bf16_t Bs[64 * 32];
    const int tid = threadIdx.x;
    const int lane = tid & 63, w = tid >> 6;
    const int lm = lane & 15, quad = lane >> 4;
    const int wy = w >> 1, wx = w & 1;
    const int bid = blockIdx.x;
    const int xcd = bid & 7, idx = bid >> 3;     // idx 0..63
    const int gm = (xcd << 2) + (idx >> 4);      // 0..31
    const int gn = idx & 15;                     // 0..15
    const int m0 = gm << 7, n0 = gn << 6;

    const floatx4 fz = {0.f, 0.f, 0.f, 0.f};
    floatx4 acc[4][2];
    #pragma unroll
    for (int i = 0; i < 4; i++)
        #pragma unroll
        for (int j = 0; j < 2; j++) acc[i][j] = fz;

    const bf16_t* Ag = yb + (size_t)m0 * Cdim;
    const bf16_t* Bg = wpT + (size_t)n0 * Cdim;

    for (int k0 = 0; k0 < Cdim; k0 += 32) {
        #pragma unroll
        for (int it = 0; it < 2; ++it) {         // A: 512 chunks
            int ci = (w << 7) + (it << 6) + lane;
            int row = ci >> 2, cq = (ci & 3) ^ (row & 3);
            async16(Ag + (size_t)row * Cdim + k0 + cq * 8, As + ((w << 7) + (it << 6)) * 8);
        }
        {                                        // B: 256 chunks (1/thread)
            int ci = tid;
            int row = ci >> 2, cq = (ci & 3) ^ (row & 3);
            async16(Bg + (size_t)row * Cdim + k0 + cq * 8, Bs + (w << 6) * 8);
        }
        __syncthreads();
        bf16x8 af[4], bfr[2];
        #pragma unroll
        for (int i = 0; i < 4; i++) {
            int row = (wy << 6) + (i << 4) + lm;
            int cq = quad ^ (lm & 3);
            af[i] = *(const bf16x8*)&As[row * 32 + cq * 8];
        }
        #pragma unroll
        for (int j = 0; j < 2; j++) {
            int row = (wx << 5) + (j << 4) + lm;
            int cq = quad ^ (lm & 3);
            bfr[j] = *(const bf16x8*)&Bs[row * 32 + cq * 8];
        }
        #pragma unroll
        for (int i = 0; i < 4; i++)
            #pragma unroll
            for (int j = 0; j < 2; j++)
                acc[i][j] = __builtin_amdgcn_mfma_f32_16x16x32_bf16(af[i], bfr[j], acc[i][j], 0, 0, 0);
        __syncthreads();
    }

    const int mb = m0 + (wy << 6);
    const int nb = n0 + (wx << 5);
    #pragma unroll
    for (int i = 0; i < 4; i++) {
        int mrow0 = mb + (i << 4) + (quad << 2);
        #pragma unroll
        for (int j = 0; j < 2; j++) {
            int n = nb + (j << 4) + lm;
            float bi = bias[n];
            #pragma unroll
            for (int r = 0; r < 4; r++)
                out[(size_t)(mrow0 + r) * Cdim + n] = acc[i][j][r] + bi;
        }
    }
}

extern "C" void kernel_launch(void* const* d_in, const int* in_sizes, int n_in,
                              void* d_out, int out_size, void* d_ws, size_t ws_size,
                              hipStream_t stream) {
    const float* x      = (const float*)d_in[0];
    const float* cosb   = (const float*)d_in[1];
    const float* sinb   = (const float*)d_in[2];
    const float* w_attn = (const float*)d_in[3];
    const float* b_attn = (const float*)d_in[4];
    const float* w_proj = (const float*)d_in[5];
    const float* b_proj = (const float*)d_in[6];

    char* ws = (char*)d_ws;
    bf16_t* xb  = (bf16_t*)(ws);                       //  8 MB: x bf16 (M,K)
    bf16_t* waT = (bf16_t*)(ws + (size_t)(8 << 20));   //  6 MB: w_attn^T (N,K)
    bf16_t* wpT = (bf16_t*)(ws + (size_t)(14 << 20));  //  2 MB: w_proj^T (N,K)
    bf16_t* qb  = (bf16_t*)(ws + (size_t)(16 << 20));  //  8 MB: q bf16 (BH,T,HD), pre-scaled
    bf16_t* kb  = (bf16_t*)(ws + (size_t)(24 << 20));  //  8 MB: k bf16 (BH,T,HD)
    bf16_t* vtb = (bf16_t*)(ws + (size_t)(32 << 20));  //  8 MB: v^T bf16 (BH,HD,T), key-permuted
    bf16_t* yb  = (bf16_t*)(ws + (size_t)(40 << 20));  //  8 MB: attn out (M,C)

    prep_kernel<<<6144, 256, 0, stream>>>(x, w_attn, w_proj, xb, waT, wpT);
    gemm_qkv<<<768, 256, 0, stream>>>(xb, waT, b_attn, cosb, sinb, qb, kb, vtb);
    attn_mfma<<<1024, 256, 0, stream>>>(qb, kb, vtb, yb);
    gemm_proj<<<512, 256, 0, stream>>>(yb, wpT, b_proj, (float*)d_out);
}

// Round 12
// 179.600 us; speedup vs baseline: 1.0698x; 1.0175x over previous
//
#include <hip/hip_runtime.h>
#include <hip/hip_bf16.h>
#include <math.h>

#define Bsz 2
#define Tseq 2048
#define Cdim 1024
#define Hn 16
#define HDim 64
#define Mrows 4096
#define N3 3072
#define QSCALE 0.1803368801111137f   /* 0.125 * log2(e) baked into Q */

typedef __bf16 bf16_t;
typedef __bf16 bf16x4 __attribute__((ext_vector_type(4)));
typedef __bf16 bf16x8 __attribute__((ext_vector_type(8)));
typedef float floatx4 __attribute__((ext_vector_type(4)));

__device__ __forceinline__ void async16(const void* g, void* l) {
    __builtin_amdgcn_global_load_lds(
        (const __attribute__((address_space(1))) void*)g,
        (__attribute__((address_space(3))) void*)l, 16, 0, 0);
}

// ---------------------------------------------------------------------------
// prep: fused fp32->bf16 convert of x + transpose-convert of w_attn, w_proj.
// blocks 0..2047: convert; 2048..5119: w_attn^T; 5120..6143: w_proj^T.
// ---------------------------------------------------------------------------
__global__ __launch_bounds__(256) void prep_kernel(
    const float* __restrict__ x, const float* __restrict__ w_attn,
    const float* __restrict__ w_proj, bf16_t* __restrict__ xb,
    bf16_t* __restrict__ waT, bf16_t* __restrict__ wpT)
{
    __shared__ float Ts[32][33];
    const int bid = blockIdx.x;
    if (bid < 2048) {
        size_t g = (size_t)bid * 256 + threadIdx.x;
        float4 a = *(const float4*)(x + g * 8);
        float4 b = *(const float4*)(x + g * 8 + 4);
        bf16x8 o;
        o[0] = (bf16_t)a.x; o[1] = (bf16_t)a.y; o[2] = (bf16_t)a.z; o[3] = (bf16_t)a.w;
        o[4] = (bf16_t)b.x; o[5] = (bf16_t)b.y; o[6] = (bf16_t)b.z; o[7] = (bf16_t)b.w;
        *(bf16x8*)(xb + g * 8) = o;
        return;
    }
    const float* in; bf16_t* out; int R, C, bx, by;
    if (bid < 5120) {
        int t = bid - 2048; in = w_attn; out = waT; R = Cdim; C = N3;
        bx = t % 96; by = t / 96;
    } else {
        int t = bid - 5120; in = w_proj; out = wpT; R = Cdim; C = Cdim;
        bx = t & 31; by = t >> 5;
    }
    int c0 = bx << 5, r0 = by << 5;
    int lr = threadIdx.x >> 3, lc = (threadIdx.x & 7) << 2;
    float4 v = *(const float4*)(in + (size_t)(r0 + lr) * C + c0 + lc);
    Ts[lr][lc] = v.x; Ts[lr][lc + 1] = v.y; Ts[lr][lc + 2] = v.z; Ts[lr][lc + 3] = v.w;
    __syncthreads();
    bf16x4 o;
    o[0] = (bf16_t)Ts[lc + 0][lr]; o[1] = (bf16_t)Ts[lc + 1][lr];
    o[2] = (bf16_t)Ts[lc + 2][lr]; o[3] = (bf16_t)Ts[lc + 3][lr];
    *(bf16x4*)(out + (size_t)(c0 + lr) * R + r0 + lc) = o;
}

// ---------------------------------------------------------------------------
// QKV GEMM = r5 body (measured 44-49us across reruns; 7 structural variants
// all regressed). m97-style loop + XCD-chunked remap (FETCH 38->21.6MB).
// Epilogue: bias + rotary(q,k) + QSCALE; v -> (BH,HD,T) sigma-permuted so
// attn's PV B-operand comes straight from P registers.
// ---------------------------------------------------------------------------
__global__ __launch_bounds__(256) void gemm_qkv(
    const bf16_t* __restrict__ xb, const bf16_t* __restrict__ waT,
    const float* __restrict__ bias, const float* __restrict__ cosb,
    const float* __restrict__ sinb,
    bf16_t* __restrict__ qb, bf16_t* __restrict__ kb, bf16_t* __restrict__ vt)
{
    __shared__ bf16_t As[128 * 32];
    __shared__ bf16_t Bs[128 * 32];
    const int tid = threadIdx.x;
    const int lane = tid & 63, w = tid >> 6;
    const int lm = lane & 15, quad = lane >> 4;
    const int wy = w >> 1, wx = w & 1;
    const int bid = blockIdx.x;
    const int xcd = bid & 7, i5 = bid >> 3;
    const int gn = ((xcd & 1) * 12) + (i5 % 12);
    const int gm = ((xcd >> 1) * 8) + (i5 / 12);
    const int m0 = gm << 7, n0 = gn << 7;

    const floatx4 fz = {0.f, 0.f, 0.f, 0.f};
    floatx4 acc[4][4];
    #pragma unroll
    for (int i = 0; i < 4; i++)
        #pragma unroll
        for (int j = 0; j < 4; j++) acc[i][j] = fz;

    const bf16_t* Ag = xb + (size_t)m0 * Cdim;
    const bf16_t* Bg = waT + (size_t)n0 * Cdim;

    for (int k0 = 0; k0 < Cdim; k0 += 32) {
        #pragma unroll
        for (int it = 0; it < 2; ++it) {
            int ci = (w << 7) + (it << 6) + lane;
            int row = ci >> 2, cq = (ci & 3) ^ (row & 3);
            async16(Ag + (size_t)row * Cdim + k0 + cq * 8, As + ((w << 7) + (it << 6)) * 8);
            async16(Bg + (size_t)row * Cdim + k0 + cq * 8, Bs + ((w << 7) + (it << 6)) * 8);
        }
        __syncthreads();
        bf16x8 af[4], bfr[4];
        #pragma unroll
        for (int i = 0; i < 4; i++) {
            int row = (wy << 6) + (i << 4) + lm;
            int cq = quad ^ (lm & 3);
            af[i] = *(const bf16x8*)&As[row * 32 + cq * 8];
        }
        #pragma unroll
        for (int j = 0; j < 4; j++) {
            int row = (wx << 6) + (j << 4) + lm;
            int cq = quad ^ (lm & 3);
            bfr[j] = *(const bf16x8*)&Bs[row * 32 + cq * 8];
        }
        #pragma unroll
        for (int i = 0; i < 4; i++)
            #pragma unroll
            for (int j = 0; j < 4; j++)
                acc[i][j] = __builtin_amdgcn_mfma_f32_16x16x32_bf16(af[i], bfr[j], acc[i][j], 0, 0, 0);
        __syncthreads();
    }

    const int sec = n0 >> 10;                 // block-uniform: 0=q 1=k 2=v
    const int mb = m0 + (wy << 6);
    const int nb = n0 + (wx << 6);
    #pragma unroll
    for (int i = 0; i < 4; i++) {
        int mrow0 = mb + (i << 4) + (quad << 2);
        int b = mrow0 >> 11, t0 = mrow0 & 2047;
        #pragma unroll
        for (int j = 0; j < 4; j++) {
            int n = nb + (j << 4) + lm;
            float bi = bias[n];
            int rel = n & 1023;
            int h = rel >> 6, hd = rel & 63;
            if (sec == 2) {
                int tp = (t0 & ~31) | (((t0 >> 2) & 3) << 3) | (((t0 >> 4) & 1) << 2);
                bf16x4 pk;
                #pragma unroll
                for (int r = 0; r < 4; r++) pk[r] = (bf16_t)(acc[i][j][r] + bi);
                *(bf16x4*)&vt[((size_t)(b * Hn + h) * HDim + hd) * Tseq + tp] = pk;
            } else {
                bf16_t* dst = (sec == 0) ? qb : kb;
                const int ih = hd >> 1;
                const bool ev = !(hd & 1);
                #pragma unroll
                for (int r = 0; r < 4; r++) {
                    int t = t0 + r;
                    float v = acc[i][j][r] + bi;
                    float x = __shfl_xor(v, 1);        // rotary pair partner
                    float c = cosb[t * 32 + ih], s = sinb[t * 32 + ih];
                    float rv = ev ? (v * c - x * s) : (x * s + v * c);
                    if (sec == 0) rv *= QSCALE;
                    dst[((size_t)(b * Hn + h) * Tseq + t) * HDim + hd] = (bf16_t)rv;
                }
            }
        }
    }
}

// ---------------------------------------------------------------------------
// Flash attention = r14 schedule (validated best), r17 content change:
// l-via-MFMA. The old softmax had a 16-deep SERIAL float-add chain
// (rs += exp2(...)) + 2 shuffles per iteration on the critical path
// (VALU-latency-bound kernel: VALUBusy ~46%, MfmaUtil ~11%). Now the
// denominator is accumulated by ONE extra MFMA per cc with an all-ones
// A-fragment: o_l = mfma(ones, pf[cc], o_l) -> every output row holds
// colsum(P) = l for q=lm (quads hold d-rows of the SAME q, so o_l[0] is
// this lane's l). 2 MFMA/iter (~20cy on the idle MFMA pipe) replaces the
// serial VALU chain, and the 16 exp2+cvt become fully independent (ILP).
// Sums bf16-rounded P — consistent with the PV numerator.
// Schedule unchanged: 3-buffer counted-vmcnt, 1 s_barrier/iter, vmcnt(4).
// ---------------------------------------------------------------------------
__global__ __launch_bounds__(256) void attn_mfma(
    const bf16_t* __restrict__ qb, const bf16_t* __restrict__ kb,
    const bf16_t* __restrict__ vt, bf16_t* __restrict__ yb)
{
    __shared__ bf16_t Ks[3][64 * 64];       // 24 KB
    __shared__ bf16_t VTs[3][64 * 64];      // 24 KB

    const int bid = blockIdx.x;
    const int jt = 31 - (bid >> 5);          // long blocks dispatch first
    const int bh = bid & 31;
    const int b = bh >> 4, h = bh & 15;
    const int tid = threadIdx.x;
    const int w4 = tid >> 6, lane = tid & 63, lm = lane & 15, quad = lane >> 4;
    const int nk = jt + 1;                   // kt = 0 .. jt (causal)

    const bf16_t* Kg0 = kb + (size_t)bh * Tseq * HDim;
    const bf16_t* Vg0 = vt + (size_t)bh * HDim * Tseq;

    // loop-invariant Q fragments (B-operand: n=lm, k); drain before staging
    const int qq = (jt << 6) + (w4 << 4) + lm;   // this lane's q row
    bf16x8 qf[2];
    {
        const bf16_t* Qg = qb + ((size_t)bh * Tseq + qq) * HDim;
        #pragma unroll
        for (int ks = 0; ks < 2; ++ks)
            qf[ks] = *(const bf16x8*)(Qg + (ks << 5) + (quad << 3));
    }
    asm volatile("s_waitcnt vmcnt(0)" ::: "memory");

    auto stagef = [&](int tile, int buf) {
        const bf16_t* Kg = Kg0 + (size_t)(tile << 6) * HDim;
        const bf16_t* Vg = Vg0 + (tile << 6);
        #pragma unroll
        for (int it = 0; it < 2; ++it) {
            int ci = (it << 8) + tid;
            int row = ci >> 3, cq = (ci & 7) ^ (row & 7);
            async16(Kg + row * HDim + cq * 8, &Ks[buf][((it << 8) + (w4 << 6)) * 8]);
            async16(Vg + (size_t)row * Tseq + cq * 8, &VTs[buf][((it << 8) + (w4 << 6)) * 8]);
        }
    };

    stagef(0, 0);                            // 4 loads/thread
    if (nk > 1) stagef(1, 1);                // 4 more

    const floatx4 fz = {0.f, 0.f, 0.f, 0.f};
    floatx4 o_[4];                           // O^T: [d-subtile]
    #pragma unroll
    for (int f = 0; f < 4; ++f) o_[f] = fz;
    floatx4 o_l = fz;                        // l accumulator (all rows = l(q))
    const bf16_t one_b = (bf16_t)1.f;
    const bf16x8 onesf = {one_b, one_b, one_b, one_b, one_b, one_b, one_b, one_b};

    int cb = 0, sb = 2;                      // cb=kt%3, sb=(kt+2)%3
    for (int kt = 0; kt < nk; ++kt) {
        if (kt == nk - 1) { asm volatile("s_waitcnt vmcnt(0)" ::: "memory"); }
        else             { asm volatile("s_waitcnt vmcnt(4)" ::: "memory"); }
        __builtin_amdgcn_s_barrier();
        __builtin_amdgcn_sched_barrier(0);
        if (kt + 2 < nk) stagef(kt + 2, sb);

        // S^T = K Q^T (rows = keys, cols = q)
        floatx4 st[4];
        #pragma unroll
        for (int sub = 0; sub < 4; ++sub) st[sub] = fz;
        #pragma unroll
        for (int ks = 0; ks < 2; ++ks) {
            bf16x8 kf[4];
            #pragma unroll
            for (int sub = 0; sub < 4; ++sub) {
                int krow = (sub << 4) + lm;
                int kc = ((ks << 2) + quad) ^ (krow & 7);
                kf[sub] = *(const bf16x8*)&Ks[cb][krow * 64 + kc * 8];
            }
            #pragma unroll
            for (int sub = 0; sub < 4; ++sub)
                st[sub] = __builtin_amdgcn_mfma_f32_16x16x32_bf16(
                    kf[sub], qf[ks], st[sub], 0, 0, 0);
        }

        // no-max softmax: P = exp2(s) (bf16); independent exp2+cvt (no
        // serial rs chain — l comes from the ones-MFMA below)
        const bool dm = (kt == jt);           // diagonal tile -> causal mask
        bf16x8 pf[2];                         // B-operand P frags (key halves)
        #pragma unroll
        for (int cc = 0; cc < 2; ++cc)
            #pragma unroll
            for (int jj = 0; jj < 8; ++jj) {
                int sub = (cc << 1) + (jj >> 2), r = jj & 3;
                float val = st[sub][r];
                if (dm) {
                    int key = (kt << 6) + (sub << 4) + (quad << 2) + r;
                    if (key > qq) val = -3e38f;
                }
                pf[cc][jj] = (bf16_t)exp2f(val);
            }

        // O^T += V^T P^T; l += colsum(P) via ones-fragment MFMA
        #pragma unroll
        for (int cc = 0; cc < 2; ++cc) {
            bf16x8 vf[4];
            #pragma unroll
            for (int f = 0; f < 4; ++f) {
                int vrow = (f << 4) + lm;
                int vc = ((cc << 2) + quad) ^ (vrow & 7);
                vf[f] = *(const bf16x8*)&VTs[cb][vrow * 64 + vc * 8];
            }
            #pragma unroll
            for (int f = 0; f < 4; ++f)
                o_[f] = __builtin_amdgcn_mfma_f32_16x16x32_bf16(
                    vf[f], pf[cc], o_[f], 0, 0, 0);
            o_l = __builtin_amdgcn_mfma_f32_16x16x32_bf16(
                onesf, pf[cc], o_l, 0, 0, 0);
        }
        sb = cb; cb = (cb == 2) ? 0 : cb + 1;
    }

    // epilogue: O^T lane holds q=qq, d = f*16+quad*4+r; o_l rows all = l(q)
    {
        float inv = 1.f / o_l[0];
        size_t base = ((size_t)(b * Tseq) + qq) * Cdim + (h << 6) + (quad << 2);
        #pragma unroll
        for (int f = 0; f < 4; ++f) {
            bf16x4 ov;
            #pragma unroll
            for (int r = 0; r < 4; ++r) ov[r] = (bf16_t)(o_[f][r] * inv);
            *(bf16x4*)&yb[base + (f << 4)] = ov;
        }
    }
}

// ---------------------------------------------------------------------------
// Proj GEMM, 128x64 tile, 512 blocks, 2/CU (measured parity with 128x128).
// ---------------------------------------------------------------------------
__global__ __launch_bounds__(256) void gemm_proj(
    const bf16_t* __restrict__ yb, const bf16_t* __restrict__ wpT,
    const float* __restrict__ bias, float* __restrict__ out)
{
    __shared__ bf16_t As[128 * 32];
    __shared__ bf16_t Bs[64 * 32];
    const int tid = threadIdx.x;
    const int lane = tid & 63, w = tid >> 6;
    const int lm = lane & 15, quad = lane >> 4;
    const int wy = w >> 1, wx = w & 1;
    const int bid = blockIdx.x;
    const int xcd = bid & 7, idx = bid >> 3;     // idx 0..63
    const int gm = (xcd << 2) + (idx >> 4);      // 0..31
    const int gn = idx & 15;                     // 0..15
    const int m0 = gm << 7, n0 = gn << 6;

    const floatx4 fz = {0.f, 0.f, 0.f, 0.f};
    floatx4 acc[4][2];
    #pragma unroll
    for (int i = 0; i < 4; i++)
        #pragma unroll
        for (int j = 0; j < 2; j++) acc[i][j] = fz;

    const bf16_t* Ag = yb + (size_t)m0 * Cdim;
    const bf16_t* Bg = wpT + (size_t)n0 * Cdim;

    for (int k0 = 0; k0 < Cdim; k0 += 32) {
        #pragma unroll
        for (int it = 0; it < 2; ++it) {         // A: 512 chunks
            int ci = (w << 7) + (it << 6) + lane;
            int row = ci >> 2, cq = (ci & 3) ^ (row & 3);
            async16(Ag + (size_t)row * Cdim + k0 + cq * 8, As + ((w << 7) + (it << 6)) * 8);
        }
        {                                        // B: 256 chunks (1/thread)
            int ci = tid;
            int row = ci >> 2, cq = (ci & 3) ^ (row & 3);
            async16(Bg + (size_t)row * Cdim + k0 + cq * 8, Bs + (w << 6) * 8);
        }
        __syncthreads();
        bf16x8 af[4], bfr[2];
        #pragma unroll
        for (int i = 0; i < 4; i++) {
            int row = (wy << 6) + (i << 4) + lm;
            int cq = quad ^ (lm & 3);
            af[i] = *(const bf16x8*)&As[row * 32 + cq * 8];
        }
        #pragma unroll
        for (int j = 0; j < 2; j++) {
            int row = (wx << 5) + (j << 4) + lm;
            int cq = quad ^ (lm & 3);
            bfr[j] = *(const bf16x8*)&Bs[row * 32 + cq * 8];
        }
        #pragma unroll
        for (int i = 0; i < 4; i++)
            #pragma unroll
            for (int j = 0; j < 2; j++)
                acc[i][j] = __builtin_amdgcn_mfma_f32_16x16x32_bf16(af[i], bfr[j], acc[i][j], 0, 0, 0);
        __syncthreads();
    }

    const int mb = m0 + (wy << 6);
    const int nb = n0 + (wx << 5);
    #pragma unroll
    for (int i = 0; i < 4; i++) {
        int mrow0 = mb + (i << 4) + (quad << 2);
        #pragma unroll
        for (int j = 0; j < 2; j++) {
            int n = nb + (j << 4) + lm;
            float bi = bias[n];
            #pragma unroll
            for (int r = 0; r < 4; r++)
                out[(size_t)(mrow0 + r) * Cdim + n] = acc[i][j][r] + bi;
        }
    }
}

extern "C" void kernel_launch(void* const* d_in, const int* in_sizes, int n_in,
                              void* d_out, int out_size, void* d_ws, size_t ws_size,
                              hipStream_t stream) {
    const float* x      = (const float*)d_in[0];
    const float* cosb   = (const float*)d_in[1];
    const float* sinb   = (const float*)d_in[2];
    const float* w_attn = (const float*)d_in[3];
    const float* b_attn = (const float*)d_in[4];
    const float* w_proj = (const float*)d_in[5];
    const float* b_proj = (const float*)d_in[6];

    char* ws = (char*)d_ws;
    bf16_t* xb  = (bf16_t*)(ws);                       //  8 MB: x bf16 (M,K)
    bf16_t* waT = (bf16_t*)(ws + (size_t)(8 << 20));   //  6 MB: w_attn^T (N,K)
    bf16_t* wpT = (bf16_t*)(ws + (size_t)(14 << 20));  //  2 MB: w_proj^T (N,K)
    bf16_t* qb  = (bf16_t*)(ws + (size_t)(16 << 20));  //  8 MB: q bf16 (BH,T,HD), pre-scaled
    bf16_t* kb  = (bf16_t*)(ws + (size_t)(24 << 20));  //  8 MB: k bf16 (BH,T,HD)
    bf16_t* vtb = (bf16_t*)(ws + (size_t)(32 << 20));  //  8 MB: v^T bf16 (BH,HD,T), key-permuted
    bf16_t* yb  = (bf16_t*)(ws + (size_t)(40 << 20));  //  8 MB: attn out (M,C)

    prep_kernel<<<6144, 256, 0, stream>>>(x, w_attn, w_proj, xb, waT, wpT);
    gemm_qkv<<<768, 256, 0, stream>>>(xb, waT, b_attn, cosb, sinb, qb, kb, vtb);
    attn_mfma<<<1024, 256, 0, stream>>>(qb, kb, vtb, yb);
    gemm_proj<<<512, 256, 0, stream>>>(yb, wpT, b_proj, (float*)d_out);
}

// Round 13
// 175.052 us; speedup vs baseline: 1.0976x; 1.0260x over previous
//
#include <hip/hip_runtime.h>
#include <hip/hip_bf16.h>
#include <math.h>

#define Bsz 2
#define Tseq 2048
#define Cdim 1024
#define Hn 16
#define HDim 64
#define Mrows 4096
#define N3 3072
#define QSCALE 0.1803368801111137f   /* 0.125 * log2(e) baked into Q */

typedef __bf16 bf16_t;
typedef __bf16 bf16x4 __attribute__((ext_vector_type(4)));
typedef __bf16 bf16x8 __attribute__((ext_vector_type(8)));
typedef float floatx4 __attribute__((ext_vector_type(4)));

__device__ __forceinline__ void async16(const void* g, void* l) {
    __builtin_amdgcn_global_load_lds(
        (const __attribute__((address_space(1))) void*)g,
        (__attribute__((address_space(3))) void*)l, 16, 0, 0);
}

// ---------------------------------------------------------------------------
// prep: fused fp32->bf16 convert of x + transpose-convert of w_attn, w_proj.
// blocks 0..2047: convert; 2048..5119: w_attn^T; 5120..6143: w_proj^T.
// ---------------------------------------------------------------------------
__global__ __launch_bounds__(256) void prep_kernel(
    const float* __restrict__ x, const float* __restrict__ w_attn,
    const float* __restrict__ w_proj, bf16_t* __restrict__ xb,
    bf16_t* __restrict__ waT, bf16_t* __restrict__ wpT)
{
    __shared__ float Ts[32][33];
    const int bid = blockIdx.x;
    if (bid < 2048) {
        size_t g = (size_t)bid * 256 + threadIdx.x;
        float4 a = *(const float4*)(x + g * 8);
        float4 b = *(const float4*)(x + g * 8 + 4);
        bf16x8 o;
        o[0] = (bf16_t)a.x; o[1] = (bf16_t)a.y; o[2] = (bf16_t)a.z; o[3] = (bf16_t)a.w;
        o[4] = (bf16_t)b.x; o[5] = (bf16_t)b.y; o[6] = (bf16_t)b.z; o[7] = (bf16_t)b.w;
        *(bf16x8*)(xb + g * 8) = o;
        return;
    }
    const float* in; bf16_t* out; int R, C, bx, by;
    if (bid < 5120) {
        int t = bid - 2048; in = w_attn; out = waT; R = Cdim; C = N3;
        bx = t % 96; by = t / 96;
    } else {
        int t = bid - 5120; in = w_proj; out = wpT; R = Cdim; C = Cdim;
        bx = t & 31; by = t >> 5;
    }
    int c0 = bx << 5, r0 = by << 5;
    int lr = threadIdx.x >> 3, lc = (threadIdx.x & 7) << 2;
    float4 v = *(const float4*)(in + (size_t)(r0 + lr) * C + c0 + lc);
    Ts[lr][lc] = v.x; Ts[lr][lc + 1] = v.y; Ts[lr][lc + 2] = v.z; Ts[lr][lc + 3] = v.w;
    __syncthreads();
    bf16x4 o;
    o[0] = (bf16_t)Ts[lc + 0][lr]; o[1] = (bf16_t)Ts[lc + 1][lr];
    o[2] = (bf16_t)Ts[lc + 2][lr]; o[3] = (bf16_t)Ts[lc + 3][lr];
    *(bf16x4*)(out + (size_t)(c0 + lr) * R + r0 + lc) = o;
}

// ---------------------------------------------------------------------------
// QKV GEMM = r5 body (measured 44-49us across reruns; 7 structural variants
// all regressed). m97-style loop + XCD-chunked remap (FETCH 38->21.6MB).
// Epilogue: bias + rotary(q,k) + QSCALE; v -> (BH,HD,T) sigma-permuted so
// attn's PV B-operand comes straight from P registers.
// ---------------------------------------------------------------------------
__global__ __launch_bounds__(256) void gemm_qkv(
    const bf16_t* __restrict__ xb, const bf16_t* __restrict__ waT,
    const float* __restrict__ bias, const float* __restrict__ cosb,
    const float* __restrict__ sinb,
    bf16_t* __restrict__ qb, bf16_t* __restrict__ kb, bf16_t* __restrict__ vt)
{
    __shared__ bf16_t As[128 * 32];
    __shared__ bf16_t Bs[128 * 32];
    const int tid = threadIdx.x;
    const int lane = tid & 63, w = tid >> 6;
    const int lm = lane & 15, quad = lane >> 4;
    const int wy = w >> 1, wx = w & 1;
    const int bid = blockIdx.x;
    const int xcd = bid & 7, i5 = bid >> 3;
    const int gn = ((xcd & 1) * 12) + (i5 % 12);
    const int gm = ((xcd >> 1) * 8) + (i5 / 12);
    const int m0 = gm << 7, n0 = gn << 7;

    const floatx4 fz = {0.f, 0.f, 0.f, 0.f};
    floatx4 acc[4][4];
    #pragma unroll
    for (int i = 0; i < 4; i++)
        #pragma unroll
        for (int j = 0; j < 4; j++) acc[i][j] = fz;

    const bf16_t* Ag = xb + (size_t)m0 * Cdim;
    const bf16_t* Bg = waT + (size_t)n0 * Cdim;

    for (int k0 = 0; k0 < Cdim; k0 += 32) {
        #pragma unroll
        for (int it = 0; it < 2; ++it) {
            int ci = (w << 7) + (it << 6) + lane;
            int row = ci >> 2, cq = (ci & 3) ^ (row & 3);
            async16(Ag + (size_t)row * Cdim + k0 + cq * 8, As + ((w << 7) + (it << 6)) * 8);
            async16(Bg + (size_t)row * Cdim + k0 + cq * 8, Bs + ((w << 7) + (it << 6)) * 8);
        }
        __syncthreads();
        bf16x8 af[4], bfr[4];
        #pragma unroll
        for (int i = 0; i < 4; i++) {
            int row = (wy << 6) + (i << 4) + lm;
            int cq = quad ^ (lm & 3);
            af[i] = *(const bf16x8*)&As[row * 32 + cq * 8];
        }
        #pragma unroll
        for (int j = 0; j < 4; j++) {
            int row = (wx << 6) + (j << 4) + lm;
            int cq = quad ^ (lm & 3);
            bfr[j] = *(const bf16x8*)&Bs[row * 32 + cq * 8];
        }
        #pragma unroll
        for (int i = 0; i < 4; i++)
            #pragma unroll
            for (int j = 0; j < 4; j++)
                acc[i][j] = __builtin_amdgcn_mfma_f32_16x16x32_bf16(af[i], bfr[j], acc[i][j], 0, 0, 0);
        __syncthreads();
    }

    const int sec = n0 >> 10;                 // block-uniform: 0=q 1=k 2=v
    const int mb = m0 + (wy << 6);
    const int nb = n0 + (wx << 6);
    #pragma unroll
    for (int i = 0; i < 4; i++) {
        int mrow0 = mb + (i << 4) + (quad << 2);
        int b = mrow0 >> 11, t0 = mrow0 & 2047;
        #pragma unroll
        for (int j = 0; j < 4; j++) {
            int n = nb + (j << 4) + lm;
            float bi = bias[n];
            int rel = n & 1023;
            int h = rel >> 6, hd = rel & 63;
            if (sec == 2) {
                int tp = (t0 & ~31) | (((t0 >> 2) & 3) << 3) | (((t0 >> 4) & 1) << 2);
                bf16x4 pk;
                #pragma unroll
                for (int r = 0; r < 4; r++) pk[r] = (bf16_t)(acc[i][j][r] + bi);
                *(bf16x4*)&vt[((size_t)(b * Hn + h) * HDim + hd) * Tseq + tp] = pk;
            } else {
                bf16_t* dst = (sec == 0) ? qb : kb;
                const int ih = hd >> 1;
                const bool ev = !(hd & 1);
                #pragma unroll
                for (int r = 0; r < 4; r++) {
                    int t = t0 + r;
                    float v = acc[i][j][r] + bi;
                    float x = __shfl_xor(v, 1);        // rotary pair partner
                    float c = cosb[t * 32 + ih], s = sinb[t * 32 + ih];
                    float rv = ev ? (v * c - x * s) : (x * s + v * c);
                    if (sec == 0) rv *= QSCALE;
                    dst[((size_t)(b * Hn + h) * Tseq + t) * HDim + hd] = (bf16_t)rv;
                }
            }
        }
    }
}

// ---------------------------------------------------------------------------
// Flash attention = r12 (best measured: 179.6 total). r14 counted-vmcnt
// schedule + l-via-MFMA (denominator via ones-fragment MFMA on the idle
// matrix pipe; removed the 16-deep serial VALU add chain + 2 shuffles).
// ---------------------------------------------------------------------------
__global__ __launch_bounds__(256) void attn_mfma(
    const bf16_t* __restrict__ qb, const bf16_t* __restrict__ kb,
    const bf16_t* __restrict__ vt, bf16_t* __restrict__ yb)
{
    __shared__ bf16_t Ks[3][64 * 64];       // 24 KB
    __shared__ bf16_t VTs[3][64 * 64];      // 24 KB

    const int bid = blockIdx.x;
    const int jt = 31 - (bid >> 5);          // long blocks dispatch first
    const int bh = bid & 31;
    const int b = bh >> 4, h = bh & 15;
    const int tid = threadIdx.x;
    const int w4 = tid >> 6, lane = tid & 63, lm = lane & 15, quad = lane >> 4;
    const int nk = jt + 1;                   // kt = 0 .. jt (causal)

    const bf16_t* Kg0 = kb + (size_t)bh * Tseq * HDim;
    const bf16_t* Vg0 = vt + (size_t)bh * HDim * Tseq;

    // loop-invariant Q fragments (B-operand: n=lm, k); drain before staging
    const int qq = (jt << 6) + (w4 << 4) + lm;   // this lane's q row
    bf16x8 qf[2];
    {
        const bf16_t* Qg = qb + ((size_t)bh * Tseq + qq) * HDim;
        #pragma unroll
        for (int ks = 0; ks < 2; ++ks)
            qf[ks] = *(const bf16x8*)(Qg + (ks << 5) + (quad << 3));
    }
    asm volatile("s_waitcnt vmcnt(0)" ::: "memory");

    auto stagef = [&](int tile, int buf) {
        const bf16_t* Kg = Kg0 + (size_t)(tile << 6) * HDim;
        const bf16_t* Vg = Vg0 + (tile << 6);
        #pragma unroll
        for (int it = 0; it < 2; ++it) {
            int ci = (it << 8) + tid;
            int row = ci >> 3, cq = (ci & 7) ^ (row & 7);
            async16(Kg + row * HDim + cq * 8, &Ks[buf][((it << 8) + (w4 << 6)) * 8]);
            async16(Vg + (size_t)row * Tseq + cq * 8, &VTs[buf][((it << 8) + (w4 << 6)) * 8]);
        }
    };

    stagef(0, 0);                            // 4 loads/thread
    if (nk > 1) stagef(1, 1);                // 4 more

    const floatx4 fz = {0.f, 0.f, 0.f, 0.f};
    floatx4 o_[4];                           // O^T: [d-subtile]
    #pragma unroll
    for (int f = 0; f < 4; ++f) o_[f] = fz;
    floatx4 o_l = fz;                        // l accumulator (all rows = l(q))
    const bf16_t one_b = (bf16_t)1.f;
    const bf16x8 onesf = {one_b, one_b, one_b, one_b, one_b, one_b, one_b, one_b};

    int cb = 0, sb = 2;                      // cb=kt%3, sb=(kt+2)%3
    for (int kt = 0; kt < nk; ++kt) {
        if (kt == nk - 1) { asm volatile("s_waitcnt vmcnt(0)" ::: "memory"); }
        else             { asm volatile("s_waitcnt vmcnt(4)" ::: "memory"); }
        __builtin_amdgcn_s_barrier();
        __builtin_amdgcn_sched_barrier(0);
        if (kt + 2 < nk) stagef(kt + 2, sb);

        // S^T = K Q^T (rows = keys, cols = q)
        floatx4 st[4];
        #pragma unroll
        for (int sub = 0; sub < 4; ++sub) st[sub] = fz;
        #pragma unroll
        for (int ks = 0; ks < 2; ++ks) {
            bf16x8 kf[4];
            #pragma unroll
            for (int sub = 0; sub < 4; ++sub) {
                int krow = (sub << 4) + lm;
                int kc = ((ks << 2) + quad) ^ (krow & 7);
                kf[sub] = *(const bf16x8*)&Ks[cb][krow * 64 + kc * 8];
            }
            #pragma unroll
            for (int sub = 0; sub < 4; ++sub)
                st[sub] = __builtin_amdgcn_mfma_f32_16x16x32_bf16(
                    kf[sub], qf[ks], st[sub], 0, 0, 0);
        }

        // no-max softmax: P = exp2(s) (bf16); independent exp2+cvt (no
        // serial rs chain — l comes from the ones-MFMA below)
        const bool dm = (kt == jt);           // diagonal tile -> causal mask
        bf16x8 pf[2];                         // B-operand P frags (key halves)
        #pragma unroll
        for (int cc = 0; cc < 2; ++cc)
            #pragma unroll
            for (int jj = 0; jj < 8; ++jj) {
                int sub = (cc << 1) + (jj >> 2), r = jj & 3;
                float val = st[sub][r];
                if (dm) {
                    int key = (kt << 6) + (sub << 4) + (quad << 2) + r;
                    if (key > qq) val = -3e38f;
                }
                pf[cc][jj] = (bf16_t)exp2f(val);
            }

        // O^T += V^T P^T; l += colsum(P) via ones-fragment MFMA
        #pragma unroll
        for (int cc = 0; cc < 2; ++cc) {
            bf16x8 vf[4];
            #pragma unroll
            for (int f = 0; f < 4; ++f) {
                int vrow = (f << 4) + lm;
                int vc = ((cc << 2) + quad) ^ (vrow & 7);
                vf[f] = *(const bf16x8*)&VTs[cb][vrow * 64 + vc * 8];
            }
            #pragma unroll
            for (int f = 0; f < 4; ++f)
                o_[f] = __builtin_amdgcn_mfma_f32_16x16x32_bf16(
                    vf[f], pf[cc], o_[f], 0, 0, 0);
            o_l = __builtin_amdgcn_mfma_f32_16x16x32_bf16(
                onesf, pf[cc], o_l, 0, 0, 0);
        }
        sb = cb; cb = (cb == 2) ? 0 : cb + 1;
    }

    // epilogue: O^T lane holds q=qq, d = f*16+quad*4+r; o_l rows all = l(q)
    {
        float inv = 1.f / o_l[0];
        size_t base = ((size_t)(b * Tseq) + qq) * Cdim + (h << 6) + (quad << 2);
        #pragma unroll
        for (int f = 0; f < 4; ++f) {
            bf16x4 ov;
            #pragma unroll
            for (int r = 0; r < 4; ++r) ov[r] = (bf16_t)(o_[f][r] * inv);
            *(bf16x4*)&yb[base + (f << 4)] = ov;
        }
    }
}

// ---------------------------------------------------------------------------
// Proj GEMM, r18: counted-vmcnt triple-buffer (validated schedule, applied
// in its SAFE regime). proj was the last kernel on the original
// stage->sync->compute->sync loop: all 32 vmcnt(0) drains exposed, no
// prefetch, only 2 co-resident blocks. Unlike the r15 qkv failure (48KB LDS
// cut 3->2 blocks/CU), proj is GRID-limited at 2 blocks/CU and 3x12KB=36KB
// (even 64KB-rounded) still fits 2 -> occupancy provably unchanged.
// Per K-step t: vmcnt(3) [drains tile t's 3 loads/thread, leaves t+1's] ->
// s_barrier -> sched_barrier(0) -> stage(t+2)->buf[(t+2)%3] -> compute(t).
// Unrolled x3, all buffer indices static (rule 20). Tail: t=30 vmcnt(3),
// t=31 vmcnt(0). WAR: stage(t+2) targets buf last read at compute(t-1),
// sealed by barrier(t). 128x64 tile, 512 blocks, XCD remap unchanged.
// ---------------------------------------------------------------------------
#define PSTAGE(AD, BD, KO) do {                                              \
    _Pragma("unroll") for (int _it = 0; _it < 2; ++_it) {                    \
        int _ci = (w << 7) + (_it << 6) + lane;                              \
        int _row = _ci >> 2, _cq = (_ci & 3) ^ (_row & 3);                   \
        async16(Ag + (size_t)_row * Cdim + (KO) + _cq * 8,                   \
                (AD) + ((w << 7) + (_it << 6)) * 8);                         \
    }                                                                        \
    {                                                                        \
        int _ci = tid;                                                       \
        int _row = _ci >> 2, _cq = (_ci & 3) ^ (_row & 3);                   \
        async16(Bg + (size_t)_row * Cdim + (KO) + _cq * 8,                   \
                (BD) + (w << 6) * 8);                                        \
    } } while (0)

#define PCOMP(AC, BC) do {                                                   \
    bf16x8 _af[4], _bf[2];                                                   \
    _Pragma("unroll") for (int _i = 0; _i < 4; _i++) {                       \
        int _row = (wy << 6) + (_i << 4) + lm;                               \
        int _cq = quad ^ (lm & 3);                                           \
        _af[_i] = *(const bf16x8*)&(AC)[_row * 32 + _cq * 8];                \
    }                                                                        \
    _Pragma("unroll") for (int _j = 0; _j < 2; _j++) {                       \
        int _row = (wx << 5) + (_j << 4) + lm;                               \
        int _cq = quad ^ (lm & 3);                                           \
        _bf[_j] = *(const bf16x8*)&(BC)[_row * 32 + _cq * 8];                \
    }                                                                        \
    _Pragma("unroll") for (int _i = 0; _i < 4; _i++)                         \
        _Pragma("unroll") for (int _j = 0; _j < 2; _j++)                     \
            acc[_i][_j] = __builtin_amdgcn_mfma_f32_16x16x32_bf16(           \
                _af[_i], _bf[_j], acc[_i][_j], 0, 0, 0);                     \
    } while (0)

#define PWAIT3 do { asm volatile("s_waitcnt vmcnt(3)" ::: "memory");         \
    __builtin_amdgcn_s_barrier(); __builtin_amdgcn_sched_barrier(0); } while (0)
#define PWAIT0 do { asm volatile("s_waitcnt vmcnt(0)" ::: "memory");         \
    __builtin_amdgcn_s_barrier(); __builtin_amdgcn_sched_barrier(0); } while (0)

__global__ __launch_bounds__(256) void gemm_proj(
    const bf16_t* __restrict__ yb, const bf16_t* __restrict__ wpT,
    const float* __restrict__ bias, float* __restrict__ out)
{
    __shared__ bf16_t As0[4096], As1[4096], As2[4096];   // 3 x 8 KB
    __shared__ bf16_t Bs0[2048], Bs1[2048], Bs2[2048];   // 3 x 4 KB
    const int tid = threadIdx.x;
    const int lane = tid & 63, w = tid >> 6;
    const int lm = lane & 15, quad = lane >> 4;
    const int wy = w >> 1, wx = w & 1;
    const int bid = blockIdx.x;
    const int xcd = bid & 7, idx = bid >> 3;     // idx 0..63
    const int gm = (xcd << 2) + (idx >> 4);      // 0..31
    const int gn = idx & 15;                     // 0..15
    const int m0 = gm << 7, n0 = gn << 6;

    const floatx4 fz = {0.f, 0.f, 0.f, 0.f};
    floatx4 acc[4][2];
    #pragma unroll
    for (int i = 0; i < 4; i++)
        #pragma unroll
        for (int j = 0; j < 2; j++) acc[i][j] = fz;

    const bf16_t* Ag = yb + (size_t)m0 * Cdim;
    const bf16_t* Bg = wpT + (size_t)n0 * Cdim;

    PSTAGE(As0, Bs0, 0);
    PSTAGE(As1, Bs1, 32);

    for (int m = 0; m < 10; ++m) {
        const int t = 3 * m;
        PWAIT3; PSTAGE(As2, Bs2, (t + 2) << 5); PCOMP(As0, Bs0);
        PWAIT3; PSTAGE(As0, Bs0, (t + 3) << 5); PCOMP(As1, Bs1);
        PWAIT3; PSTAGE(As1, Bs1, (t + 4) << 5); PCOMP(As2, Bs2);
    }
    PWAIT3; PCOMP(As0, Bs0);               // t = 30
    PWAIT0; PCOMP(As1, Bs1);               // t = 31

    const int mb = m0 + (wy << 6);
    const int nb = n0 + (wx << 5);
    #pragma unroll
    for (int i = 0; i < 4; i++) {
        int mrow0 = mb + (i << 4) + (quad << 2);
        #pragma unroll
        for (int j = 0; j < 2; j++) {
            int n = nb + (j << 4) + lm;
            float bi = bias[n];
            #pragma unroll
            for (int r = 0; r < 4; r++)
                out[(size_t)(mrow0 + r) * Cdim + n] = acc[i][j][r] + bi;
        }
    }
}

extern "C" void kernel_launch(void* const* d_in, const int* in_sizes, int n_in,
                              void* d_out, int out_size, void* d_ws, size_t ws_size,
                              hipStream_t stream) {
    const float* x      = (const float*)d_in[0];
    const float* cosb   = (const float*)d_in[1];
    const float* sinb   = (const float*)d_in[2];
    const float* w_attn = (const float*)d_in[3];
    const float* b_attn = (const float*)d_in[4];
    const float* w_proj = (const float*)d_in[5];
    const float* b_proj = (const float*)d_in[6];

    char* ws = (char*)d_ws;
    bf16_t* xb  = (bf16_t*)(ws);                       //  8 MB: x bf16 (M,K)
    bf16_t* waT = (bf16_t*)(ws + (size_t)(8 << 20));   //  6 MB: w_attn^T (N,K)
    bf16_t* wpT = (bf16_t*)(ws + (size_t)(14 << 20));  //  2 MB: w_proj^T (N,K)
    bf16_t* qb  = (bf16_t*)(ws + (size_t)(16 << 20));  //  8 MB: q bf16 (BH,T,HD), pre-scaled
    bf16_t* kb  = (bf16_t*)(ws + (size_t)(24 << 20));  //  8 MB: k bf16 (BH,T,HD)
    bf16_t* vtb = (bf16_t*)(ws + (size_t)(32 << 20));  //  8 MB: v^T bf16 (BH,HD,T), key-permuted
    bf16_t* yb  = (bf16_t*)(ws + (size_t)(40 << 20));  //  8 MB: attn out (M,C)

    prep_kernel<<<6144, 256, 0, stream>>>(x, w_attn, w_proj, xb, waT, wpT);
    gemm_qkv<<<768, 256, 0, stream>>>(xb, waT, b_attn, cosb, sinb, qb, kb, vtb);
    attn_mfma<<<1024, 256, 0, stream>>>(qb, kb, vtb, yb);
    gemm_proj<<<512, 256, 0, stream>>>(yb, wpT, b_proj, (float*)d_out);
}